// Round 1
// baseline (956.351 us; speedup 1.0000x reference)
//
#include <hip/hip_runtime.h>
#include <math.h>

#define BATCH 16
#define CDIM 256
#define NCLS 80
#define N3 16384
#define N4 4096
#define N5 1024
#define NTOK 21504
#define KQ 300
#define KSEL 512
#define CANDMAX 1024

typedef __attribute__((ext_vector_type(8))) short short8;
typedef __attribute__((ext_vector_type(4))) float floatx4;
typedef unsigned short ushort_t;

__device__ __forceinline__ float sigmoidf_(float x) {
    return 1.0f / (1.0f + __expf(-x));
}

__device__ __forceinline__ ushort_t f2bf(float f) {   // RNE f32->bf16
    unsigned int x = __float_as_uint(f);
    unsigned int r = (x + 0x7FFFu + ((x >> 16) & 1u)) >> 16;
    return (ushort_t)r;
}

__device__ __forceinline__ void gload16(const void* g, void* l) {
    __builtin_amdgcn_global_load_lds(
        (const __attribute__((address_space(1))) unsigned int*)g,
        (__attribute__((address_space(3))) unsigned int*)l,
        16, 0, 0);
}

__device__ __forceinline__ void locate_level(
    int n, int bb,
    const float* __restrict__ s3, const float* __restrict__ s4, const float* __restrict__ s5,
    const float*& src, int& nloc, int& lsz)
{
    if (n < N3)           { src = s3 + (size_t)bb * CDIM * N3; nloc = n;           lsz = N3; }
    else if (n < N3 + N4) { src = s4 + (size_t)bb * CDIM * N4; nloc = n - N3;      lsz = N4; }
    else                  { src = s5 + (size_t)bb * CDIM * N5; nloc = n - N3 - N4; lsz = N5; }
}

// -------- Kernel 0: transpose+cast weights to bf16 W^T[col][k], PRE-SWIZZLED --------
// Swizzle: within each col's 256-u16 row, 16B chunk index c' = (k>>3) ^ (col&7).
// enc stages these via global_load_lds (linear LDS copy) and un-swizzles on the
// ds_read_b128 side -> 8-phase b128 floor instead of 16-way bank conflict.
__global__ __launch_bounds__(256) void prep_weights(
    const float* __restrict__ w1, const float* __restrict__ w2,
    const float* __restrict__ w_score,
    ushort_t* __restrict__ w1T, ushort_t* __restrict__ w2T, ushort_t* __restrict__ wsT)
{
    const int k = threadIdx.x;
    const int c = blockIdx.x;
    const int klo = k & 7;
    if (c < 256) {
        const size_t d = (size_t)c * 256 + ((((k >> 3) ^ (c & 7)) << 3) | klo);
        w1T[d] = f2bf(w1[k * 256 + c]);
    } else if (c < 512) {
        const int c2 = c - 256;
        const size_t d = (size_t)c2 * 256 + ((((k >> 3) ^ (c2 & 7)) << 3) | klo);
        w2T[d] = f2bf(w2[k * 256 + c2]);
    } else {
        const int c2 = c - 512;
        const size_t d = (size_t)c2 * 256 + ((((k >> 3) ^ (c2 & 7)) << 3) | klo);
        wsT[d] = (c2 < NCLS) ? f2bf(w_score[k * NCLS + c2]) : (ushort_t)0;
    }
}

// -------- Kernel 1: fused encoder head, bf16 MFMA, 2-phase DMA-staged pipeline --------
// grid: BATCH * 336 blocks (64 tokens each), 256 threads = 4 waves (16 tokens/wave)
// 19 flat weight chunks (3 wsT + 8 w1T + 8 w2T), double-buffered wbufL,
// global_load_lds prefetch of chunk i+1 issued before MFMA of chunk i,
// ONE __syncthreads per chunk (its implicit vmcnt(0) drains the DMA).
__global__ __launch_bounds__(256, 2) void enc_mfma_kernel(
    const float* __restrict__ s3, const float* __restrict__ s4, const float* __restrict__ s5,
    const ushort_t* __restrict__ w1T, const ushort_t* __restrict__ w2T,
    const ushort_t* __restrict__ wsT,
    const float* __restrict__ b_score, const float* __restrict__ b1,
    const float* __restrict__ b2,
    const float* __restrict__ w3, const float* __restrict__ b3,
    float* __restrict__ out_logits, float* __restrict__ out_sboxes,
    float* __restrict__ ws_scores)
{
    // ldsA: first memB[k=256][tok=68pad] bf16; later reused as h1buf[tok=64][264pad]
    __shared__ __align__(16) ushort_t ldsA[256 * 68];       // 34816 B
    __shared__ __align__(16) ushort_t wbufL[2][32 * 256];   // 2 x 16384 B (linear, DMA dest)
    __shared__ float bsc_s[96];
    __shared__ float b1_s[256];
    __shared__ float b2_s[256];
    __shared__ __align__(16) float w3_s[256 * 4];

    const int t = threadIdx.x;
    const int lane = t & 63;
    const int w = t >> 6;                 // wave id: tokens [16w,16w+16)
    const int ml = lane & 15;             // MFMA m/n lane index
    const int quad = lane >> 4;           // 0..3
    const int kq = quad * 8;              // k base within a K=32 fragment
    const int m8 = ml & 7;                // read-side swizzle key

    const int bb = blockIdx.x / 336;
    const int tile = blockIdx.x % 336;
    const int T0 = tile * 64;

    // async stage one 32-col x 256-k chunk (16 KB) into wbufL[dbuf] (linear copy)
    auto stage_async = [&](const ushort_t* wg, int dbuf) {
        const char* g = (const char*)wg + w * 1024 + (lane << 4);
        char* l = (char*)&wbufL[dbuf][0] + w * 1024;   // wave-uniform LDS base
        #pragma unroll
        for (int i = 0; i < 4; ++i)
            gload16(g + i * 4096, l + i * 4096);
    };

    // kick off chunk 0 DMA immediately — in flight during memB staging
    stage_async(wsT, 0);

    // bias / w3 preload to LDS (keeps the main loop free of stray vmem loads)
    if (t < 96) bsc_s[t] = b_score[t];
    b1_s[t] = b1[t];
    b2_s[t] = b2[t];
    *(float4*)&w3_s[t * 4] = *(const float4*)(w3 + t * 4);

    const float* src; int nloc, lsz;
    locate_level(T0, bb, s3, s4, s5, src, nloc, lsz);

    // ---- stage memory tile [k][tok] f32 -> bf16 LDS ----
    {
        const int tokq = t & 15;          // float4 group along tokens
        const int kr = t >> 4;
        #pragma unroll
        for (int p = 0; p < 16; ++p) {
            const int k = p * 16 + kr;
            const float4 v = *(const float4*)(src + (size_t)k * lsz + nloc + 4 * tokq);
            const unsigned int lo = (unsigned int)f2bf(v.x) | ((unsigned int)f2bf(v.y) << 16);
            const unsigned int hi = (unsigned int)f2bf(v.z) | ((unsigned int)f2bf(v.w) << 16);
            *(uint2*)&ldsA[k * 68 + 4 * tokq] = make_uint2(lo, hi);
        }
    }
    __syncthreads();   // drains memB writes + bias writes + chunk0 DMA

    // ---- A1 fragments: memory[tok=16w+ml][k] (reused for GEMM1+GEMM2) ----
    short8 af[8];
    #pragma unroll
    for (int f = 0; f < 8; ++f) {
        short8 a;
        #pragma unroll
        for (int j = 0; j < 8; ++j)
            a[j] = (short)ldsA[(32 * f + kq + j) * 68 + 16 * w + ml];
        af[f] = a;
    }

    const int tokl0 = 16 * w + quad * 4;
    const int tokg0 = bb * NTOK + T0 + tokl0;

    float smax[4] = {-1e30f, -1e30f, -1e30f, -1e30f};
    float psum[4][4];
    #pragma unroll
    for (int r = 0; r < 4; ++r)
        #pragma unroll
        for (int c = 0; c < 4; ++c) psum[r][c] = 0.f;

    int cur = 0;
    for (int i = 0; i < 19; ++i) {
        // issue DMA prefetch of next chunk into the other buffer.
        // safe: previous iteration's reads of that buffer completed at its barrier.
        if (i + 1 < 19) {
            const int j = i + 1;
            const ushort_t* nxt = (j < 3)  ? (wsT + (size_t)j * 8192)
                                : (j < 11) ? (w1T + (size_t)(j - 3) * 8192)
                                           : (w2T + (size_t)(j - 11) * 8192);
            stage_async(nxt, cur ^ 1);
        }

        // A2 fragments for GEMM3: h1buf complete as of barrier at end of i==10
        if (i == 11) {
            #pragma unroll
            for (int f = 0; f < 8; ++f)
                af[f] = *(const short8*)&ldsA[(16 * w + ml) * 264 + 32 * f + kq];
        }

        const ushort_t* wb = &wbufL[cur][0];
        #pragma unroll
        for (int tt = 0; tt < 2; ++tt) {
            if (i < 3 && (2 * i + tt) >= 5) continue;    // wsT padding cols 80..95
            const int row = 16 * tt + ml;
            floatx4 acc = {0.f, 0.f, 0.f, 0.f};
            #pragma unroll
            for (int f = 0; f < 8; ++f) {
                const short8 bf = *(const short8*)&wb[row * 256 + (((4 * f + quad) ^ m8) << 3)];
                acc = __builtin_amdgcn_mfma_f32_16x16x32_bf16(af[f], bf, acc, 0, 0, 0);
            }
            if (i < 3) {
                // GEMM1 epilogue: logits + per-row running max
                const int col = 16 * (2 * i + tt) + ml;
                const float bias = bsc_s[col];
                #pragma unroll
                for (int r = 0; r < 4; ++r) {
                    const float v = acc[r] + bias;
                    out_logits[(size_t)(tokg0 + r) * NCLS + col] = v;
                    smax[r] = fmaxf(smax[r], v);
                }
            } else if (i < 11) {
                // GEMM2 epilogue: h1 = relu(...) -> h1buf (ldsA reused [tok][264])
                const int col = 32 * (i - 3) + 16 * tt + ml;
                const float bias = b1_s[col];
                #pragma unroll
                for (int r = 0; r < 4; ++r) {
                    const float v = fmaxf(acc[r] + bias, 0.f);
                    ldsA[(tokl0 + r) * 264 + col] = f2bf(v);
                }
            } else {
                // GEMM3 epilogue: h2 = relu(...); boxes = h2 @ w3 folded in-register
                const int col = 32 * (i - 11) + 16 * tt + ml;
                const float bias = b2_s[col];
                const float4 w3v = *(const float4*)&w3_s[col * 4];
                #pragma unroll
                for (int r = 0; r < 4; ++r) {
                    const float v = fmaxf(acc[r] + bias, 0.f);
                    psum[r][0] = fmaf(v, w3v.x, psum[r][0]);
                    psum[r][1] = fmaf(v, w3v.y, psum[r][1]);
                    psum[r][2] = fmaf(v, w3v.z, psum[r][2]);
                    psum[r][3] = fmaf(v, w3v.w, psum[r][3]);
                }
            }
        }

        if (i == 2) {
            // GEMM1 done: reduce per-row max over the 16 col-lanes, emit score
            #pragma unroll
            for (int r = 0; r < 4; ++r) {
                float m = smax[r];
                m = fmaxf(m, __shfl_xor(m, 1));
                m = fmaxf(m, __shfl_xor(m, 2));
                m = fmaxf(m, __shfl_xor(m, 4));
                m = fmaxf(m, __shfl_xor(m, 8));
                smax[r] = m;
            }
            if (ml == 0) {
                #pragma unroll
                for (int r = 0; r < 4; ++r)
                    ws_scores[bb * NTOK + T0 + 16 * w + quad * 4 + r] = sigmoidf_(smax[r]);
            }
        }

        __syncthreads();   // implicit vmcnt(0)+lgkmcnt(0): DMA of chunk i+1 done,
                           // all reads of wbufL[cur] done, h1 writes visible
        cur ^= 1;
    }

    // reduce boxes partials over the 16 lanes holding different col subsets
    #pragma unroll
    for (int r = 0; r < 4; ++r)
        #pragma unroll
        for (int c = 0; c < 4; ++c) {
            float v = psum[r][c];
            v += __shfl_xor(v, 1);
            v += __shfl_xor(v, 2);
            v += __shfl_xor(v, 4);
            v += __shfl_xor(v, 8);
            psum[r][c] = v;
        }
    if (ml == 0) {
        #pragma unroll
        for (int r = 0; r < 4; ++r) {
            float4 o;
            o.x = sigmoidf_(psum[r][0] + b3[0]);
            o.y = sigmoidf_(psum[r][1] + b3[1]);
            o.z = sigmoidf_(psum[r][2] + b3[2]);
            o.w = sigmoidf_(psum[r][3] + b3[3]);
            *(float4*)&out_sboxes[(size_t)(bb * NTOK + T0 + 16 * w + quad * 4 + r) * 4] = o;
        }
    }
}

// -------- Kernel 2: fp32 radix pre-select of top-KSEL candidates per batch --------
// All scores lie in [0.5,1) -> pass-0 keys share one bin. Wave-aggregate equal
// bins via leader/ballot so a same-bin wave issues ONE atomic, not 64 serialized.
__global__ __launch_bounds__(1024) void select_kernel(
    const float* __restrict__ scores,
    int* __restrict__ cand_idx, unsigned int* __restrict__ cand_cnt)
{
    const int bb = blockIdx.x;
    const int t = threadIdx.x;
    const int lane = t & 63;
    const float* s = scores + bb * NTOK;

    __shared__ unsigned int hist[256];
    __shared__ unsigned int prefix_s, rem_s, cnt_s;

    unsigned int prefix = 0, mask = 0;
    int remaining = KSEL;
    for (int pass = 0; pass < 4; pass++) {
        const int shift = 24 - 8 * pass;
        if (t < 256) hist[t] = 0;
        __syncthreads();
        for (int n = t; n < NTOK; n += 1024) {          // NTOK % 1024 == 0
            const unsigned int key = __float_as_uint(s[n]);
            const bool pred = ((key & mask) == prefix);
            const unsigned int bin = (key >> shift) & 255u;
            unsigned long long alive = __ballot(pred);
            while (alive) {
                const int leader = __builtin_ctzll(alive);
                const unsigned int lbin = (unsigned int)__shfl((int)bin, leader);
                const unsigned long long match = alive & __ballot(bin == lbin);
                if (lane == leader)
                    atomicAdd(&hist[lbin], (unsigned int)__popcll(match));
                alive &= ~match;
            }
        }
        __syncthreads();
        if (t == 0) {
            int rem = remaining; unsigned int bsel = 0;
            for (int bin = 255; bin >= 0; bin--) {
                int c = (int)hist[bin];
                if (c >= rem) { bsel = (unsigned int)bin; break; }
                rem -= c;
            }
            prefix_s = prefix | (bsel << shift);
            rem_s = (unsigned int)rem;
        }
        __syncthreads();
        prefix = prefix_s; remaining = (int)rem_s;
        mask |= 0xFFu << shift;
        __syncthreads();
    }
    const unsigned int Tkey = prefix;

    if (t == 0) cnt_s = 0;
    __syncthreads();
    for (int n = t; n < NTOK; n += 1024) {
        const unsigned int key = __float_as_uint(s[n]);
        const bool pred = (key >= Tkey);
        const unsigned long long m = __ballot(pred);
        if (m) {
            const int leader = __builtin_ctzll(m);
            unsigned int base = 0;
            if (lane == leader) base = atomicAdd(&cnt_s, (unsigned int)__popcll(m));
            base = (unsigned int)__shfl((int)base, leader);
            if (pred) {
                const unsigned int pos =
                    base + (unsigned int)__popcll(m & ((1ull << lane) - 1ull));
                if (pos < CANDMAX) cand_idx[bb * CANDMAX + pos] = n;
            }
        }
    }
    __syncthreads();
    if (t == 0) {
        unsigned int c = cnt_s; if (c > CANDMAX) c = CANDMAX;
        cand_cnt[bb] = c;
    }
}

// -------- Kernel 3: f64 exact rescore (one wave per candidate) --------
__global__ __launch_bounds__(256) void rescore_kernel(
    const float* __restrict__ s3, const float* __restrict__ s4, const float* __restrict__ s5,
    const float* __restrict__ w_score, const float* __restrict__ b_score,
    const int* __restrict__ cand_idx, const unsigned int* __restrict__ cand_cnt,
    double* __restrict__ cand_score)
{
    __shared__ float mrow[4][CDIM];
    const int t = threadIdx.x;
    const int w = t >> 6;
    const int lane = t & 63;
    const int bb = blockIdx.x / (CANDMAX / 4);
    const int c  = (blockIdx.x % (CANDMAX / 4)) * 4 + w;
    const unsigned int cnt = cand_cnt[bb];
    const bool active = (unsigned int)c < cnt;

    int n = 0;
    if (active) n = cand_idx[bb * CANDMAX + c];
    if (active) {
        const float* src; int nloc, lsz;
        locate_level(n, bb, s3, s4, s5, src, nloc, lsz);
        #pragma unroll
        for (int j = 0; j < 4; j++)
            mrow[w][4 * lane + j] = src[(size_t)(4 * lane + j) * lsz + nloc];
    }
    __syncthreads();

    if (active) {
        double acc0 = (double)b_score[lane];
        double acc1 = (lane < 16) ? (double)b_score[64 + lane] : -1.0e300;
        for (int k = 0; k < CDIM; k++) {
            const double m = (double)mrow[w][k];
            acc0 += m * (double)w_score[k * NCLS + lane];
            if (lane < 16) acc1 += m * (double)w_score[k * NCLS + 64 + lane];
        }
        double mx = fmax(acc0, acc1);
        mx = fmax(mx, __shfl_xor(mx, 1));
        mx = fmax(mx, __shfl_xor(mx, 2));
        mx = fmax(mx, __shfl_xor(mx, 4));
        mx = fmax(mx, __shfl_xor(mx, 8));
        mx = fmax(mx, __shfl_xor(mx, 16));
        mx = fmax(mx, __shfl_xor(mx, 32));
        if (lane == 0) cand_score[bb * CANDMAX + c] = mx;
    }
}

// -------- Kernel 4: exact sort of candidates, emit top-300 --------
__global__ __launch_bounds__(256) void fsort_kernel(
    const double* __restrict__ cand_score, const int* __restrict__ cand_idx,
    const unsigned int* __restrict__ cand_cnt,
    float* __restrict__ out_idx_f, float* __restrict__ out_scores,
    int* __restrict__ ws_idx)
{
    __shared__ double ss[CANDMAX];
    __shared__ int    ii[CANDMAX];
    const int bb = blockIdx.x;
    const int t = threadIdx.x;
    const unsigned int cnt = cand_cnt[bb];

    for (int i = t; i < CANDMAX; i += 256) {
        if ((unsigned int)i < cnt) {
            ss[i] = cand_score[bb * CANDMAX + i];
            ii[i] = cand_idx[bb * CANDMAX + i];
        } else {
            ss[i] = -1.0e300;
            ii[i] = 0x7FFFFFFF;
        }
    }
    __syncthreads();

    for (int ksz = 2; ksz <= CANDMAX; ksz <<= 1) {
        for (int j = ksz >> 1; j > 0; j >>= 1) {
            #pragma unroll
            for (int p = 0; p < CANDMAX / 256; p++) {
                const int i = p * 256 + t;
                const int ixj = i ^ j;
                if (ixj > i) {
                    double sa = ss[i], sb = ss[ixj];
                    int ia = ii[i], ib = ii[ixj];
                    const bool up = ((i & ksz) != 0);
                    const bool agtb = (sa > sb) || (sa == sb && ia < ib);
                    if (agtb == up) { ss[i] = sb; ss[ixj] = sa; ii[i] = ib; ii[ixj] = ia; }
                }
            }
            __syncthreads();
        }
    }

    for (int q = t; q < KQ; q += 256) {
        const double x = ss[q];
        const int idx = ii[q];
        out_scores[bb * KQ + q] = (float)(1.0 / (1.0 + exp(-x)));
        out_idx_f[bb * KQ + q] = (float)idx;
        ws_idx[bb * KQ + q] = idx;
    }
}

// -------- Kernel 5: gather top-k memory rows, project, gather ref_points --------
__global__ __launch_bounds__(256) void gather_proj_kernel(
    const float* __restrict__ s3, const float* __restrict__ s4, const float* __restrict__ s5,
    const float* __restrict__ w_proj, const float* __restrict__ b_proj,
    const int* __restrict__ ws_idx, const float* __restrict__ out_sboxes,
    float* __restrict__ out_tgt, float* __restrict__ out_ref)
{
    __shared__ float memQ[20][CDIM];
    __shared__ int qidx[20];
    const int t = threadIdx.x;
    const int bb = blockIdx.x / 15;
    const int tile = blockIdx.x % 15;
    const int q0 = tile * 20;

    if (t < 20) qidx[t] = ws_idx[bb * KQ + q0 + t];
    __syncthreads();

    #pragma unroll 4
    for (int q = 0; q < 20; q++) {
        const int n = qidx[q];
        const float* src; int nloc, lsz;
        locate_level(n, bb, s3, s4, s5, src, nloc, lsz);
        memQ[q][t] = src[(size_t)t * lsz + nloc];
    }
    __syncthreads();

    const int j = t;
    float acc[20];
    #pragma unroll
    for (int q = 0; q < 20; q++) acc[q] = b_proj[j];
    for (int k = 0; k < CDIM; k++) {
        const float w = w_proj[(size_t)k * CDIM + j];
        #pragma unroll
        for (int q = 0; q < 20; q++) acc[q] = fmaf(memQ[q][k], w, acc[q]);
    }
    #pragma unroll
    for (int q = 0; q < 20; q++)
        out_tgt[(size_t)(bb * KQ + q0 + q) * CDIM + j] = acc[q];

    if (t < 80) {
        const int q = t >> 2, c = t & 3;
        const int n = qidx[q];
        out_ref[(size_t)(bb * KQ + q0 + q) * 4 + c] =
            out_sboxes[(size_t)(bb * NTOK + n) * 4 + c];
    }
}

extern "C" void kernel_launch(void* const* d_in, const int* in_sizes, int n_in,
                              void* d_out, int out_size, void* d_ws, size_t ws_size,
                              hipStream_t stream) {
    const float* s3      = (const float*)d_in[0];
    const float* s4      = (const float*)d_in[1];
    const float* s5      = (const float*)d_in[2];
    const float* w_score = (const float*)d_in[3];
    const float* b_score = (const float*)d_in[4];
    const float* w1      = (const float*)d_in[5];
    const float* b1      = (const float*)d_in[6];
    const float* w2      = (const float*)d_in[7];
    const float* b2      = (const float*)d_in[8];
    const float* w3      = (const float*)d_in[9];
    const float* b3      = (const float*)d_in[10];
    const float* w_proj  = (const float*)d_in[11];
    const float* b_proj  = (const float*)d_in[12];

    float* out = (float*)d_out;
    float* out_tgt    = out;                 // 16*300*256
    float* out_ref    = out + 1228800;       // 16*300*4
    float* out_logits = out + 1248000;       // 16*21504*80
    float* out_sboxes = out + 28773120;      // 16*21504*4
    float* out_idx    = out + 30149376;      // 16*300 (as float)
    float* out_scores = out + 30154176;      // 16*300

    char* ws = (char*)d_ws;
    float*        ws_scores  = (float*)(ws + 0);            // 1,376,256
    double*       cand_score = (double*)(ws + 1376256);     //   131,072
    int*          cand_idx   = (int*)(ws + 1507328);        //    65,536
    unsigned int* cand_cnt   = (unsigned int*)(ws + 1572864); //      256
    int*          ws_idx     = (int*)(ws + 1573120);        //    19,456
    ushort_t*     w1T        = (ushort_t*)(ws + 1592576);   //   131,072
    ushort_t*     w2T        = (ushort_t*)(ws + 1723648);   //   131,072
    ushort_t*     wsT        = (ushort_t*)(ws + 1854720);   //    49,152

    prep_weights<<<608, 256, 0, stream>>>(w1, w2, w_score, w1T, w2T, wsT);

    enc_mfma_kernel<<<BATCH * 336, 256, 0, stream>>>(
        s3, s4, s5, w1T, w2T, wsT, b_score, b1, b2, w3, b3,
        out_logits, out_sboxes, ws_scores);

    select_kernel<<<BATCH, 1024, 0, stream>>>(ws_scores, cand_idx, cand_cnt);

    rescore_kernel<<<BATCH * (CANDMAX / 4), 256, 0, stream>>>(
        s3, s4, s5, w_score, b_score, cand_idx, cand_cnt, cand_score);

    fsort_kernel<<<BATCH, 256, 0, stream>>>(
        cand_score, cand_idx, cand_cnt, out_idx, out_scores, ws_idx);

    gather_proj_kernel<<<BATCH * 15, 256, 0, stream>>>(
        s3, s4, s5, w_proj, b_proj, ws_idx, out_sboxes, out_tgt, out_ref);
}